// Round 7
// baseline (359.353 us; speedup 1.0000x reference)
//
#include <hip/hip_runtime.h>
#include <hip/hip_bf16.h>
#include <cstdint>
#include <cstddef>

typedef __attribute__((ext_vector_type(8))) __bf16 bf16x8;
typedef __attribute__((ext_vector_type(4))) __bf16 bf16x4;
typedef __attribute__((ext_vector_type(8))) _Float16 halfx8;
typedef __attribute__((ext_vector_type(4))) float  floatx4;

#define MFMA16x16x32(a, b, c) __builtin_amdgcn_mfma_f32_16x16x32_bf16((a), (b), (c), 0, 0, 0)

#define ATTN_SC 0.18033688011112042f  // (1/sqrt(64)) * log2(e), folded into Q projection

__device__ __forceinline__ void gload_lds16(const void* g, void* l) {
  __builtin_amdgcn_global_load_lds((const __attribute__((address_space(1))) void*)g,
                                   (__attribute__((address_space(3))) void*)l,
                                   16, 0, 0);
}

// ---------------- fused prep: weight casts + conv-weight pack + ktmp row0 + x cast ----------------

__global__ void prep_kernel(const float* __restrict__ x,
                            const float* __restrict__ Wq, const float* __restrict__ Wk,
                            const float* __restrict__ Wv, const float* __restrict__ Wo,
                            const float* __restrict__ Wconv,
                            __bf16* __restrict__ xb,
                            __bf16* __restrict__ wqb, __bf16* __restrict__ wkb,
                            __bf16* __restrict__ wvb, __bf16* __restrict__ wob,
                            __bf16* __restrict__ wc2, __bf16* __restrict__ ktmp,
                            unsigned* __restrict__ cnt) {
  const int bid = blockIdx.x, tid = threadIdx.x;
  if (bid == 0 && tid == 0) *cnt = 0;   // persistent-convq work counter
  if (bid < 4096) {
    const int which = bid >> 10;
    const float* src = (which == 0) ? Wq : (which == 1) ? Wk : (which == 2) ? Wv : Wo;
    __bf16* dst = (which == 0) ? wqb : (which == 1) ? wkb : (which == 2) ? wvb : wob;
    const int i = (bid & 1023) * 256 + tid;  // < 262144 quads
    floatx4 v = *(const floatx4*)(src + (size_t)i * 4);
    bf16x4 o; o[0] = (__bf16)v[0]; o[1] = (__bf16)v[1]; o[2] = (__bf16)v[2]; o[3] = (__bf16)v[3];
    *(bf16x4*)(dst + (size_t)i * 4) = o;
  } else if (bid < 5120) {
    const int t = (bid - 4096) * 256 + tid;  // < 262144
    const int o = t >> 8, c = t & 255;
    const float* base = Wconv + (size_t)o * 3072 + c * 12;
    float f[12];
    *(floatx4*)(f)     = *(const floatx4*)(base);
    *(floatx4*)(f + 4) = *(const floatx4*)(base + 4);
    *(floatx4*)(f + 8) = *(const floatx4*)(base + 8);
#pragma unroll
    for (int kw = 0; kw < 3; ++kw) {
      bf16x4 q;
#pragma unroll
      for (int j = 0; j < 4; ++j) q[j] = (__bf16)f[3 * j + kw];
      *(bf16x4*)(wc2 + (size_t)o * 3072 + kw * 1024 + c * 4) = q;
    }
  } else if (bid < 5136) {
    const int i = (bid - 5120) * 256 + tid;  // < 4096 : k_tmp[b,0,:] = x[b,0,:]
    const int b = i >> 10, c = i & 1023;
    ktmp[(size_t)b * 1025 * 1024 + c] = (__bf16)x[(size_t)b * 3072 * 1024 + c];
  } else {
    const int i = (bid - 5136) * 256 + tid;  // < 3145728 quads
    floatx4 v = *(const floatx4*)(x + (size_t)i * 4);
    bf16x4 o; o[0] = (__bf16)v[0]; o[1] = (__bf16)v[1]; o[2] = (__bf16)v[2]; o[3] = (__bf16)v[3];
    *(bf16x4*)(xb + (size_t)i * 4) = o;
  }
}

// V (b*1025+t, 1024) -> Vt[(b*16+h)*64 + d][t], t in [0,1024)
__global__ void vtrans_kernel(const __bf16* __restrict__ V, __bf16* __restrict__ Vt) {
  __shared__ __attribute__((aligned(16))) __bf16 tile[64][72];
  const int tid = threadIdx.x;
  const int bh = blockIdx.y;
  const int b = bh >> 4, h = bh & 15;
  const int t0 = blockIdx.x * 64;
  const int r = tid >> 3, s = tid & 7;
#pragma unroll
  for (int p = 0; p < 2; ++p) {
    const int t = p * 32 + r;
    bf16x8 v = *(const bf16x8*)(V + ((size_t)(b * 1025 + t0 + t)) * 1024 + h * 64 + s * 8);
    *(bf16x8*)(&tile[t][s * 8]) = v;
  }
  __syncthreads();
#pragma unroll
  for (int p = 0; p < 2; ++p) {
    const int d = p * 32 + r;
    bf16x8 o;
#pragma unroll
    for (int e = 0; e < 8; ++e) o[e] = tile[s * 8 + e][d];
    *(bf16x8*)(Vt + ((size_t)bh * 64 + d) * 1024 + t0 + s * 8) = o;
  }
}

// ---------------- 256x256 GEMM body (m201 geometry): C = A[M,K] @ Bw[N,K]^T ----------------
// BK=64, double-buffered 128 KB LDS. 512 threads = 8 waves (2M x 4N), per-wave 128x64
// (acc[8][4]): reads/MFMA = 0.375 b128 (vs 0.5 at 64x64 -> the r1-r6 LDS-port wall).
// Chunk-XOR swizzle chunk' = chunk ^ (row&7); ra&7 == ln&7 for all frag rows -> constant
// per-lane XOR. Staging = 8 gload_lds per K-tile issued across phases 0-2 of the PREVIOUS
// tile's compute (~2 phases of slack -> the per-tile vmcnt(0) is nearly free).
// Quadrant read-ahead: frags for quad q+1 issue before MFMA quad q -> LDS pipe overlaps
// MFMA pipe within each wave. Sync = 2 barriers + 1 vmcnt per K-tile (512 wave-MFMAs).
// MODE 0: bf16 (rows < mMax). 1: bf16 conv remap. 2: fp32+bias. 4: bf16*ATTN_SC. 5: fp16.

template <int MODE>
__device__ __forceinline__ void gemm256_body(
    const __bf16* __restrict__ A, const __bf16* __restrict__ Bw, void* __restrict__ Cout,
    const float* __restrict__ bias, int lda, int ldb, int m0, int n0, int mMax,
    __bf16* As, __bf16* Bs)
{
  const int tid  = threadIdx.x;
  const int wave = tid >> 6;
  const int lane = tid & 63;
  const int g    = lane >> 4;
  const int ln   = lane & 15;
  const int wr   = (wave >> 2) * 128;
  const int wc   = (wave & 3) * 64;

  // staging: thread writes linear LDS chunk (a*512 + tid); source inverse-swizzled
  const int prow = tid >> 3;                 // 0..63 within one 64-row gload
  const int ca   = (tid & 7) ^ (prow & 7);
  const size_t aS = (size_t)(m0 + prow) * lda + ca * 8;
  const size_t bS = (size_t)(n0 + prow) * ldb + ca * 8;
  const size_t a64 = (size_t)64 * lda, b64 = (size_t)64 * ldb;

  // per-lane swizzled chunk offsets for kstep 0/1 (logical chunk 4c+g, rows ra&7==ln&7)
  const int sx0 = ((g ^ (ln & 7)) << 3);
  const int sx1 = (((4 + g) ^ (ln & 7)) << 3);

  floatx4 acc[8][4];
#pragma unroll
  for (int i = 0; i < 8; ++i)
#pragma unroll
    for (int j = 0; j < 4; ++j) { floatx4 z = {0.f, 0.f, 0.f, 0.f}; acc[i][j] = z; }

  auto STG_A = [&](int t, int buf, int a) {
    gload_lds16(A + aS + a * a64 + (size_t)t * 64, As + (buf << 14) + (a << 12) + (tid << 3));
  };
  auto STG_B = [&](int t, int buf, int a) {
    gload_lds16(Bw + bS + a * b64 + (size_t)t * 64, Bs + (buf << 14) + (a << 12) + (tid << 3));
  };

  bf16x8 bfr[4][2];
  bf16x8 aE[2][2], aO[2][2];

#define RD_B(Bb)                                                                   \
  { _Pragma("unroll")                                                              \
    for (int j_ = 0; j_ < 4; ++j_) {                                               \
      bfr[j_][0] = *(const bf16x8*)((Bb) + (wc + 16 * j_ + ln) * 64 + sx0);        \
      bfr[j_][1] = *(const bf16x8*)((Bb) + (wc + 16 * j_ + ln) * 64 + sx1);        \
    } }

#define RD_A(SET, Ab, q)                                                           \
  { _Pragma("unroll")                                                              \
    for (int i_ = 0; i_ < 2; ++i_) {                                               \
      SET[i_][0] = *(const bf16x8*)((Ab) + (wr + 16 * (2 * (q) + i_) + ln) * 64 + sx0); \
      SET[i_][1] = *(const bf16x8*)((Ab) + (wr + 16 * (2 * (q) + i_) + ln) * 64 + sx1); \
    } }

#define MF_Q(SET, q)                                                               \
  { __builtin_amdgcn_s_setprio(1);                                                 \
    _Pragma("unroll")                                                              \
    for (int c_ = 0; c_ < 2; ++c_)                                                 \
      _Pragma("unroll")                                                            \
      for (int i_ = 0; i_ < 2; ++i_)                                               \
        _Pragma("unroll")                                                          \
        for (int j_ = 0; j_ < 4; ++j_)                                             \
          acc[2 * (q) + i_][j_] = MFMA16x16x32(SET[i_][c_], bfr[j_][c_], acc[2 * (q) + i_][j_]); \
    __builtin_amdgcn_s_setprio(0); }

  const int NT = 16;  // all calls: K = 1024 = 16 K-tiles

  // prologue: stage tile 0 -> buf 0
  STG_A(0, 0, 0); STG_A(0, 0, 1); STG_A(0, 0, 2); STG_A(0, 0, 3);
  STG_B(0, 0, 0); STG_B(0, 0, 1); STG_B(0, 0, 2); STG_B(0, 0, 3);
  asm volatile("s_waitcnt vmcnt(0)" ::: "memory");
  __builtin_amdgcn_s_barrier();
  __builtin_amdgcn_sched_barrier(0);
  RD_A(aE, As, 0);

  for (int t = 0; t < NT; ++t) {
    const int buf = t & 1;
    const __bf16* Ab  = As + (buf << 14);
    const __bf16* Bb  = Bs + (buf << 14);
    const __bf16* Abn = As + ((buf ^ 1) << 14);
    const bool more = (t + 1 < NT);
    // phase 0: MFMA q0 (aE); read B(t) + A q1; stage 3
    if (more) { STG_A(t + 1, buf ^ 1, 0); STG_A(t + 1, buf ^ 1, 1); STG_B(t + 1, buf ^ 1, 0); }
    RD_B(Bb);
    RD_A(aO, Ab, 1);
    MF_Q(aE, 0);
    // phase 1: MFMA q1 (aO); read A q2; stage 3
    if (more) { STG_A(t + 1, buf ^ 1, 2); STG_A(t + 1, buf ^ 1, 3); STG_B(t + 1, buf ^ 1, 1); }
    RD_A(aE, Ab, 2);
    MF_Q(aO, 1);
    // phase 2: MFMA q2 (aE); read A q3; stage 2
    if (more) { STG_B(t + 1, buf ^ 1, 2); STG_B(t + 1, buf ^ 1, 3); }
    RD_A(aO, Ab, 3);
    MF_Q(aE, 2);
    // phase 3: certify t+1 landed (issued >=1 phase ago), read its quad0, MFMA q3
    if (more) {
      asm volatile("s_waitcnt vmcnt(0)" ::: "memory");
      __builtin_amdgcn_s_barrier();            // all waves' t+1 DMAs landed
      __builtin_amdgcn_sched_barrier(0);
      RD_A(aE, Abn, 0);                        // in flight during MFMA q3
    }
    MF_Q(aO, 3);
    __builtin_amdgcn_s_barrier();              // all waves consumed buf(t) -> WAR-safe
    __builtin_amdgcn_sched_barrier(0);
  }

#undef RD_B
#undef RD_A
#undef MF_Q

  // ---- epilogue ----
#pragma unroll
  for (int j = 0; j < 4; ++j) {
    const int col = n0 + wc + j * 16 + ln;
    float bj = 0.f;
    if (MODE == 2) bj = bias[col];
#pragma unroll
    for (int i = 0; i < 8; ++i)
#pragma unroll
      for (int r = 0; r < 4; ++r) {
        const int row = m0 + wr + i * 16 + g * 4 + r;
        if (MODE == 2) {
          ((float*)Cout)[(size_t)row * 1024 + col] = acc[i][j][r] + bj;
        } else if (MODE == 1) {
          const size_t orow = (size_t)(row >> 10) * 1025 + 1 + (row & 1023);
          ((__bf16*)Cout)[orow * 1024 + col] = (__bf16)acc[i][j][r];
        } else if (MODE == 4) {
          ((__bf16*)Cout)[(size_t)row * 1024 + col] = (__bf16)(acc[i][j][r] * ATTN_SC);
        } else if (MODE == 5) {
          ((_Float16*)Cout)[(size_t)row * 1024 + col] = (_Float16)acc[i][j][r];
        } else {
          if (row < mMax) ((__bf16*)Cout)[(size_t)row * 1024 + col] = (__bf16)acc[i][j][r];
        }
      }
  }
}

// persistent fused conv (3 kw-taps, K=1024 each) + Q GEMM: 384 uniform 16-Ktile items
// pulled by 256 blocks via atomic counter. Taps 0/1 -> fp16 partials (P0/P1 alias the
// dead kb/vb regions), tap 2 -> bf16 ktmp (remapped rows); reduce kernel sums.
__global__ __launch_bounds__(512, 2) void gemm_convq_kernel(
    const __bf16* __restrict__ xb, const __bf16* __restrict__ wc2,
    const __bf16* __restrict__ wqb, __bf16* __restrict__ ktmp, __bf16* __restrict__ qb,
    _Float16* __restrict__ P0, _Float16* __restrict__ P1, unsigned* __restrict__ cnt)
{
  __shared__ __attribute__((aligned(16))) __bf16 As[32768];
  __shared__ __attribute__((aligned(16))) __bf16 Bs[32768];
  __shared__ unsigned widx;
  for (;;) {
    if (threadIdx.x == 0) widx = atomicAdd(cnt, 1u);
    __syncthreads();
    const unsigned it = widx;
    __syncthreads();
    if (it >= 384u) break;
    if (it < 192u) {
      const int tap = (int)it >> 6, tile = (int)it & 63;
      const int m0 = (tile >> 2) * 256, n0 = (tile & 3) * 256;
      if (tap == 2)
        gemm256_body<1>(xb + 2048, wc2 + 2048, ktmp, nullptr, 3072, 3072, m0, n0, 1 << 30, As, Bs);
      else if (tap == 1)
        gemm256_body<5>(xb + 1024, wc2 + 1024, P1, nullptr, 3072, 3072, m0, n0, 1 << 30, As, Bs);
      else
        gemm256_body<5>(xb, wc2, P0, nullptr, 3072, 3072, m0, n0, 1 << 30, As, Bs);
    } else {
      const int qid = (int)it - 192;
      gemm256_body<4>(xb, wqb, qb, nullptr, 1024, 1024, (qid >> 2) * 256, (qid & 3) * 256,
                      1 << 30, As, Bs);
    }
  }
}

// ktmp[orow] += P0 + P1 (in-place, elementwise; row0 per batch untouched)
__global__ void reduce_conv_kernel(const _Float16* __restrict__ P0, const _Float16* __restrict__ P1,
                                   __bf16* __restrict__ ktmp) {
  const int idx = blockIdx.x * 256 + threadIdx.x;   // < 524288
  const int r = idx >> 7;                           // 0..4095
  const int c = (idx & 127) * 8;
  const size_t orow = (size_t)(r >> 10) * 1025 + 1 + (r & 1023);
  __bf16* kp = ktmp + orow * 1024 + c;
  bf16x8 k8 = *(const bf16x8*)kp;
  halfx8 p0 = *(const halfx8*)(P0 + (size_t)r * 1024 + c);
  halfx8 p1 = *(const halfx8*)(P1 + (size_t)r * 1024 + c);
  bf16x8 o;
#pragma unroll
  for (int e = 0; e < 8; ++e) o[e] = (__bf16)((float)k8[e] + (float)p0[e] + (float)p1[e]);
  *(bf16x8*)kp = o;
}

// K + V projections: 17 row-tiles (rows 0..4351; >=4100 garbage, stores guarded) x 4 x 2.
__global__ __launch_bounds__(512, 2) void gemm_kv_kernel(
    const __bf16* __restrict__ ktmp, const __bf16* __restrict__ wkb,
    const __bf16* __restrict__ wvb, __bf16* __restrict__ kb, __bf16* __restrict__ vb)
{
  __shared__ __attribute__((aligned(16))) __bf16 As[32768];
  __shared__ __attribute__((aligned(16))) __bf16 Bs[32768];
  const int id = (blockIdx.x & 7) * 17 + (blockIdx.x >> 3);
  const int p  = (id >= 68) ? 1 : 0;
  const int rest = id - p * 68;
  gemm256_body<0>(ktmp, p ? wvb : wkb, p ? vb : kb, nullptr, 1024, 1024,
                  (rest >> 2) * 256, (rest & 3) * 256, 4100, As, Bs);
}

__global__ __launch_bounds__(512, 2) void gemm_o_kernel(
    const __bf16* __restrict__ ob, const __bf16* __restrict__ wob,
    float* __restrict__ out, const float* __restrict__ bo)
{
  __shared__ __attribute__((aligned(16))) __bf16 As[32768];
  __shared__ __attribute__((aligned(16))) __bf16 Bs[32768];
  const int id = (blockIdx.x & 7) * 24 + (blockIdx.x >> 3);
  gemm256_body<2>(ob, wob, out, bo, 1024, 1024, (id >> 2) * 256, (id & 3) * 256, 1 << 30, As, Bs);
}

// ---------------- flash attention (unchanged from r6) ----------------

__global__ __launch_bounds__(256) void attn_kernel(
    const __bf16* __restrict__ Q, const __bf16* __restrict__ Kk,
    const __bf16* __restrict__ Vt, __bf16* __restrict__ O)
{
  __shared__ __attribute__((aligned(16))) __bf16 Kd[2][64 * 64];  // [key][d]
  __shared__ __attribute__((aligned(16))) __bf16 Vd[2][64 * 64];  // [d][key]
  __shared__ __attribute__((aligned(16))) __bf16 Ps[4][32 * 64];

  const int tid  = threadIdx.x;
  const int wave = tid >> 6;
  const int lane = tid & 63;
  const int g    = lane >> 4;
  const int ln   = lane & 15;

  const int l    = blockIdx.x;
  const int xcd  = l & 7;
  const int b    = xcd >> 1;
  const int rest = l >> 3;
  const int h    = rest & 15;
  const int qt   = ((11 - (rest >> 4)) << 1) | (xcd & 1);
  const int q0   = qt * 128 + wave * 32;

  const size_t qrow0 = (size_t)b * 3072 + q0;
  const size_t krow0 = (size_t)b * 1025;
  const size_t vtrow = ((size_t)(b * 16 + h)) * 64;
  const int hc = h * 64;
  const int sw = (ln & 7) << 3;
  __bf16* Pw = Ps[wave];

  const int srow = lane >> 3;
  const int scol = (lane & 7) * 8;

  auto stage = [&](int kt, int bb) {
    const int kb0 = kt * 64;
#pragma unroll
    for (int i = 0; i < 2; ++i) {
      const int rr = (wave * 2 + i) * 8 + srow;
      gload_lds16(Kk + (krow0 + kb0 + rr) * 1024 + hc + scol,
                  Kd[bb] + (size_t)rr * 64 + scol);
      gload_lds16(Vt + (vtrow + rr) * 1024 + kb0 + scol,
                  Vd[bb] + (size_t)rr * 64 + scol);
    }
  };

  bf16x8 qf[2][2];
#pragma unroll
  for (int i = 0; i < 2; ++i)
#pragma unroll
    for (int kc = 0; kc < 2; ++kc)
      qf[i][kc] = *(const bf16x8*)(Q + (qrow0 + i * 16 + ln) * 1024 + hc + kc * 32 + g * 8);

  floatx4 oacc[2][4];
  floatx4 oal[2];
#pragma unroll
  for (int i = 0; i < 2; ++i) {
    floatx4 z = {0.f, 0.f, 0.f, 0.f};
    oal[i] = z;
#pragma unroll
    for (int dt = 0; dt < 4; ++dt) oacc[i][dt] = z;
  }

  bf16x8 ones;
#pragma unroll
  for (int e = 0; e < 8; ++e) ones[e] = (__bf16)1.0f;

  const int nkt_blk = (((qt * 128 + 127) / 3) >> 6) + 1;
  const int nfull   = (q0 >= 189) ? ((q0 - 189) / 192 + 1) : 0;

  stage(0, 0);

  for (int kt = 0; kt < nkt_blk; ++kt) {
    const int bb = kt & 1;
    __syncthreads();
    if (kt + 1 < nkt_blk) stage(kt + 1, bb ^ 1);
    const int kb0 = kt * 64;
    const bool masked = (kt >= nfull);

    bf16x8 kf[4][2];
#pragma unroll
    for (int jk = 0; jk < 4; ++jk)
#pragma unroll
      for (int kc = 0; kc < 2; ++kc)
        kf[jk][kc] = *(const bf16x8*)(Kd[bb] + (jk * 16 + ln) * 64 + kc * 32 + g * 8);

#pragma unroll
    for (int jk = 0; jk < 4; ++jk)
#pragma unroll
      for (int i = 0; i < 2; ++i) {
        floatx4 s = {0.f, 0.f, 0.f, 0.f};
        s = MFMA16x16x32(kf[jk][0], qf[i][0], s);
        s = MFMA16x16x32(kf[jk][1], qf[i][1], s);
        float p[4];
#pragma unroll
        for (int r = 0; r < 4; ++r) {
          float e = __builtin_amdgcn_exp2f(s[r]);
          if (masked) {
            const int key = kb0 + jk * 16 + 4 * g + r;
            const int q   = q0 + i * 16 + ln;
            e = (3 * key <= q) ? e : 0.f;
          }
          p[r] = e;
        }
        bf16x4 pk;
        pk[0] = (__bf16)p[0]; pk[1] = (__bf16)p[1]; pk[2] = (__bf16)p[2]; pk[3] = (__bf16)p[3];
        *(bf16x4*)(Pw + (i * 16 + ln) * 64 + ((jk * 16 + 4 * g) ^ sw)) = pk;
      }

#pragma unroll
    for (int kc = 0; kc < 2; ++kc) {
      bf16x8 pf0 = *(const bf16x8*)(Pw + (ln) * 64      + ((kc * 32 + g * 8) ^ sw));
      bf16x8 pf1 = *(const bf16x8*)(Pw + (16 + ln) * 64 + ((kc * 32 + g * 8) ^ sw));
      oal[0] = MFMA16x16x32(ones, pf0, oal[0]);
      oal[1] = MFMA16x16x32(ones, pf1, oal[1]);
#pragma unroll
      for (int dt = 0; dt < 4; ++dt) {
        bf16x8 vf = *(const bf16x8*)(Vd[bb] + (dt * 16 + ln) * 64 + kc * 32 + g * 8);
        oacc[0][dt] = MFMA16x16x32(vf, pf0, oacc[0][dt]);
        oacc[1][dt] = MFMA16x16x32(vf, pf1, oacc[1][dt]);
      }
    }
  }

#pragma unroll
  for (int i = 0; i < 2; ++i) {
    const float inv = 1.0f / oal[i][0];
    const size_t row = qrow0 + i * 16 + ln;
#pragma unroll
    for (int dt = 0; dt < 4; ++dt) {
      bf16x4 o4;
#pragma unroll
      for (int r = 0; r < 4; ++r) o4[r] = (__bf16)(oacc[i][dt][r] * inv);
      *(bf16x4*)(O + row * 1024 + hc + dt * 16 + 4 * g) = o4;
    }
  }
}

// ---------------- host ----------------

extern "C" void kernel_launch(void* const* d_in, const int* in_sizes, int n_in,
                              void* d_out, int out_size, void* d_ws, size_t ws_size,
                              hipStream_t stream) {
  (void)in_sizes; (void)n_in; (void)out_size; (void)ws_size;
  const float* x     = (const float*)d_in[0];
  const float* Wq    = (const float*)d_in[1];
  const float* Wk    = (const float*)d_in[2];
  const float* Wv    = (const float*)d_in[3];
  const float* Wo    = (const float*)d_in[4];
  const float* bo    = (const float*)d_in[5];
  const float* Wconv = (const float*)d_in[6];

  char* ws = (char*)d_ws;
  const size_t SZ_XQ = (size_t)12288 * 1024 * 2;
  const size_t SZ_KT = (size_t)4224 * 1024 * 2;
  const size_t SZ_W  = (size_t)1024 * 1024 * 2;

  __bf16* xb   = (__bf16*)(ws);
  __bf16* qb   = (__bf16*)(ws + SZ_XQ);           // q proj (pre-scaled); attn output in-place
  __bf16* ktmp = (__bf16*)(ws + 2 * SZ_XQ);
  __bf16* kb   = (__bf16*)(ws + 2 * SZ_XQ + SZ_KT);
  __bf16* vb   = (__bf16*)(ws + 2 * SZ_XQ + 2 * SZ_KT);
  __bf16* wqb  = (__bf16*)(ws + 2 * SZ_XQ + 3 * SZ_KT);
  __bf16* wkb  = (__bf16*)(ws + 2 * SZ_XQ + 3 * SZ_KT + SZ_W);
  __bf16* wvb  = (__bf16*)(ws + 2 * SZ_XQ + 3 * SZ_KT + 2 * SZ_W);
  __bf16* wob  = (__bf16*)(ws + 2 * SZ_XQ + 3 * SZ_KT + 3 * SZ_W);
  __bf16* wc2  = (__bf16*)(ws + 2 * SZ_XQ + 3 * SZ_KT + 4 * SZ_W);
  __bf16* vt   = xb;  // xb dead after conv+q GEMMs; reuse for Vt (8.4 MB)

  _Float16* P0 = (_Float16*)kb;   // conv tap-0 partials (kb dead until kv)
  _Float16* P1 = (_Float16*)vb;   // conv tap-1 partials (vb dead until kv)
  unsigned* cnt = (unsigned*)((char*)ktmp + 8396800);  // dead corner of ktmp (rows >= 4100)

  prep_kernel<<<dim3(17424), dim3(256), 0, stream>>>(x, Wq, Wk, Wv, Wo, Wconv,
                                                     xb, wqb, wkb, wvb, wob, wc2, ktmp, cnt);
  gemm_convq_kernel<<<dim3(256), dim3(512), 0, stream>>>(xb, wc2, wqb, ktmp, qb, P0, P1, cnt);
  reduce_conv_kernel<<<dim3(2048), dim3(256), 0, stream>>>(P0, P1, ktmp);
  gemm_kv_kernel<<<dim3(136), dim3(512), 0, stream>>>(ktmp, wkb, wvb, kb, vb);
  vtrans_kernel<<<dim3(16, 64), dim3(256), 0, stream>>>(vb, vt);
  attn_kernel<<<dim3(1536), dim3(256), 0, stream>>>(qb, kb, vt, qb);
  gemm_o_kernel<<<dim3(192), dim3(512), 0, stream>>>(qb, wob, (float*)d_out, bo);
}

// Round 8
// 314.391 us; speedup vs baseline: 1.1430x; 1.1430x over previous
//
#include <hip/hip_runtime.h>
#include <hip/hip_bf16.h>
#include <cstdint>
#include <cstddef>

typedef __attribute__((ext_vector_type(8))) __bf16 bf16x8;
typedef __attribute__((ext_vector_type(4))) __bf16 bf16x4;
typedef __attribute__((ext_vector_type(4))) float  floatx4;

#define MFMA16x16x32(a, b, c) __builtin_amdgcn_mfma_f32_16x16x32_bf16((a), (b), (c), 0, 0, 0)

#define ATTN_SC 0.18033688011112042f  // (1/sqrt(64)) * log2(e), folded into Q projection

__device__ __forceinline__ void gload_lds16(const void* g, void* l) {
  __builtin_amdgcn_global_load_lds((const __attribute__((address_space(1))) void*)g,
                                   (__attribute__((address_space(3))) void*)l,
                                   16, 0, 0);
}

// ---------------- fused prep: weight casts + conv-weight pack + ktmp row0 + x cast ----------------

__global__ void prep_kernel(const float* __restrict__ x,
                            const float* __restrict__ Wq, const float* __restrict__ Wk,
                            const float* __restrict__ Wv, const float* __restrict__ Wo,
                            const float* __restrict__ Wconv,
                            __bf16* __restrict__ xb,
                            __bf16* __restrict__ wqb, __bf16* __restrict__ wkb,
                            __bf16* __restrict__ wvb, __bf16* __restrict__ wob,
                            __bf16* __restrict__ wc2, __bf16* __restrict__ ktmp) {
  const int bid = blockIdx.x, tid = threadIdx.x;
  if (bid < 4096) {
    const int which = bid >> 10;
    const float* src = (which == 0) ? Wq : (which == 1) ? Wk : (which == 2) ? Wv : Wo;
    __bf16* dst = (which == 0) ? wqb : (which == 1) ? wkb : (which == 2) ? wvb : wob;
    const int i = (bid & 1023) * 256 + tid;  // < 262144 quads
    floatx4 v = *(const floatx4*)(src + (size_t)i * 4);
    bf16x4 o; o[0] = (__bf16)v[0]; o[1] = (__bf16)v[1]; o[2] = (__bf16)v[2]; o[3] = (__bf16)v[3];
    *(bf16x4*)(dst + (size_t)i * 4) = o;
  } else if (bid < 5120) {
    const int t = (bid - 4096) * 256 + tid;  // < 262144
    const int o = t >> 8, c = t & 255;
    const float* base = Wconv + (size_t)o * 3072 + c * 12;
    float f[12];
    *(floatx4*)(f)     = *(const floatx4*)(base);
    *(floatx4*)(f + 4) = *(const floatx4*)(base + 4);
    *(floatx4*)(f + 8) = *(const floatx4*)(base + 8);
#pragma unroll
    for (int kw = 0; kw < 3; ++kw) {
      bf16x4 q;
#pragma unroll
      for (int j = 0; j < 4; ++j) q[j] = (__bf16)f[3 * j + kw];
      *(bf16x4*)(wc2 + (size_t)o * 3072 + kw * 1024 + c * 4) = q;
    }
  } else if (bid < 5136) {
    const int i = (bid - 5120) * 256 + tid;  // < 4096 : k_tmp[b,0,:] = x[b,0,:]
    const int b = i >> 10, c = i & 1023;
    ktmp[(size_t)b * 1025 * 1024 + c] = (__bf16)x[(size_t)b * 3072 * 1024 + c];
  } else {
    const int i = (bid - 5136) * 256 + tid;  // < 3145728 quads
    floatx4 v = *(const floatx4*)(x + (size_t)i * 4);
    bf16x4 o; o[0] = (__bf16)v[0]; o[1] = (__bf16)v[1]; o[2] = (__bf16)v[2]; o[3] = (__bf16)v[3];
    *(bf16x4*)(xb + (size_t)i * 4) = o;
  }
}

// V (b*1025+t, 1024) -> Vt[(b*16+h)*64 + d][t], t in [0,1024)
__global__ void vtrans_kernel(const __bf16* __restrict__ V, __bf16* __restrict__ Vt) {
  __shared__ __attribute__((aligned(16))) __bf16 tile[64][72];
  const int tid = threadIdx.x;
  const int bh = blockIdx.y;
  const int b = bh >> 4, h = bh & 15;
  const int t0 = blockIdx.x * 64;
  const int r = tid >> 3, s = tid & 7;
#pragma unroll
  for (int p = 0; p < 2; ++p) {
    const int t = p * 32 + r;
    bf16x8 v = *(const bf16x8*)(V + ((size_t)(b * 1025 + t0 + t)) * 1024 + h * 64 + s * 8);
    *(bf16x8*)(&tile[t][s * 8]) = v;
  }
  __syncthreads();
#pragma unroll
  for (int p = 0; p < 2; ++p) {
    const int d = p * 32 + r;
    bf16x8 o;
#pragma unroll
    for (int e = 0; e < 8; ++e) o[e] = tile[s * 8 + e][d];
    *(bf16x8*)(Vt + ((size_t)bh * 64 + d) * 1024 + t0 + s * 8) = o;
  }
}

// ---------------- pipelined GEMM body: C[M,N] = A[M,K] @ Bw[N,K]^T ----------------
// BM=128, BN=256, half-K=32. THREE half-K LDS slots (72 KB/block) -> 2 blocks/CU
// (r6 verified: cross-block overlap -> 1283 cyc/phase vs 1772 at 1 block/CU).
// CHANGE vs r6 (only variable this round): 4 waves of 128x64 per-wave tiles instead
// of 8 waves of 64x64 -> 12 ds_read_b128 per 32 MFMA (0.375) vs 8 per 16 (0.5),
// cutting the LDS-read-port floor by 20% on a port-bound kernel. 256 threads;
// 2 blocks/CU keeps 8 waves/CU. acc[8][4] = 128 VGPR, total ~210 (< 256 @ 2 w/SIMD).
// Same slots, swizzle, depth-2 prefetch, counted vmcnt (6 DMAs/stage), grids as r6.
// MODE 0: bf16 out. 1: bf16 out, conv row remap. 2: fp32 out + bias. 4: bf16 * ATTN_SC.

template <int MODE>
__device__ __forceinline__ void gemm4_body(
    const __bf16* __restrict__ A, const __bf16* __restrict__ Bw, void* __restrict__ Cout,
    const float* __restrict__ bias, int N, int K, int m0, int n0,
    __bf16* As, __bf16* Bs)
{
  const int tid  = threadIdx.x;   // 0..255
  const int wave = tid >> 6;      // 0..3
  const int lane = tid & 63;
  const int g    = lane >> 4;
  const int ln   = lane & 15;
  const int wc   = wave * 64;     // wave owns rows 0..127, cols wc..wc+63

  // staging: thread writes linear LDS chunks {tid, tid+256} (A) and
  // {tid, tid+256, tid+512, tid+768} (B); source = inverse-swizzled logical element.
  // chunk c: phys row pr=c>>3, phys chunk pc=c&7, logical chunk ca=pc^(pr&7);
  // A logical row = pr + 64*(ca>>2), B logical row = pr + 128*(ca>>2); col = (ca&3)*8.
  size_t aSrcv[2], bSrcv[4];
#pragma unroll
  for (int q = 0; q < 2; ++q) {
    const int c = tid + q * 256, pr = c >> 3, ca = (c & 7) ^ (pr & 7);
    aSrcv[q] = (size_t)(m0 + pr + ((ca >> 2) << 6)) * K + ((ca & 3) << 3);
  }
#pragma unroll
  for (int q = 0; q < 4; ++q) {
    const int c = tid + q * 256, pr = c >> 3, ca = (c & 7) ^ (pr & 7);
    bSrcv[q] = (size_t)(n0 + pr + ((ca >> 2) << 7)) * K + ((ca & 3) << 3);
  }

  // ds_read fragment element offsets (within a half-slot), swizzled
  int aOff[8], bOff[4];
#pragma unroll
  for (int i = 0; i < 8; ++i) {
    const int ra = i * 16 + ln;
    const int pr = ra & 63;
    const int c  = ((ra >> 6) << 2) + g;
    aOff[i] = pr * 64 + ((c ^ (pr & 7)) << 3);
  }
#pragma unroll
  for (int j = 0; j < 4; ++j) {
    const int rb = wc + j * 16 + ln;
    const int pr = rb & 127;
    const int c  = ((rb >> 7) << 2) + g;
    bOff[j] = pr * 64 + ((c ^ (pr & 7)) << 3);
  }

  floatx4 acc[8][4];
#pragma unroll
  for (int i = 0; i < 8; ++i)
#pragma unroll
    for (int j = 0; j < 4; ++j) { floatx4 z = {0.f, 0.f, 0.f, 0.f}; acc[i][j] = z; }

  // stage half t (K offset t*32) into half-slot s (0..2): 6 DMAs/thread
  auto STAGE = [&](int t, int s) {
    const int koff = t * 32;
    __bf16* ad = As + s * 4096 + (tid << 3);
    __bf16* bd = Bs + s * 8192 + (tid << 3);
    gload_lds16(A  + aSrcv[0] + koff, ad);
    gload_lds16(A  + aSrcv[1] + koff, ad + 2048);
    gload_lds16(Bw + bSrcv[0] + koff, bd);
    gload_lds16(Bw + bSrcv[1] + koff, bd + 2048);
    gload_lds16(Bw + bSrcv[2] + koff, bd + 4096);
    gload_lds16(Bw + bSrcv[3] + koff, bd + 6144);
  };

  bf16x8 af[8], bf[4];

#define READF(s)                                                                   \
  {                                                                                \
    const __bf16* ah_ = As + (s) * 4096;                                           \
    const __bf16* bh_ = Bs + (s) * 8192;                                           \
    _Pragma("unroll")                                                              \
    for (int i_ = 0; i_ < 8; ++i_) af[i_] = *(const bf16x8*)(ah_ + aOff[i_]);      \
    _Pragma("unroll")                                                              \
    for (int j_ = 0; j_ < 4; ++j_) bf[j_] = *(const bf16x8*)(bh_ + bOff[j_]);      \
  }

#define MFMAC()                                                                    \
  {                                                                                \
    __builtin_amdgcn_s_setprio(1);                                                 \
    _Pragma("unroll")                                                              \
    for (int i_ = 0; i_ < 8; ++i_)                                                 \
      _Pragma("unroll")                                                            \
      for (int j_ = 0; j_ < 4; ++j_)                                               \
        acc[i_][j_] = MFMA16x16x32(af[i_], bf[j_], acc[i_][j_]);                   \
    __builtin_amdgcn_s_setprio(0);                                                 \
  }

  const int HT = K >> 5;  // K-halves: 96 (conv) or 32 (others)

  // prologue: 2 halves in flight (12 DMAs)
  STAGE(0, 0);
  STAGE(1, 1);
  asm volatile("s_waitcnt vmcnt(6)" ::: "memory");  // half 0 landed (wave-local)
  __builtin_amdgcn_s_barrier();                     // half 0 landed (all waves)
  __builtin_amdgcn_sched_barrier(0);

  int sp = 0;  // slot of phase h
  for (int h = 0; h < HT; ++h) {
    const int s2 = (sp + 2 >= 3) ? sp - 1 : sp + 2;  // slot of h+2 == slot of h-1
    READF(sp);
    if (h + 2 < HT) STAGE(h + 2, s2);
    MFMAC();
    if (h + 1 < HT) {
      if (h + 2 < HT) { asm volatile("s_waitcnt vmcnt(6) lgkmcnt(0)" ::: "memory"); }
      else            { asm volatile("s_waitcnt vmcnt(0) lgkmcnt(0)" ::: "memory"); }
      __builtin_amdgcn_s_barrier();
      __builtin_amdgcn_sched_barrier(0);
    }
    sp = (sp + 1 >= 3) ? 0 : sp + 1;
  }

#undef READF
#undef MFMAC

  // ---- epilogue ----
#pragma unroll
  for (int j = 0; j < 4; ++j) {
    const int col = n0 + wc + j * 16 + ln;
    float bj = 0.f;
    if (MODE == 2) bj = bias[col];
#pragma unroll
    for (int i = 0; i < 8; ++i)
#pragma unroll
      for (int r = 0; r < 4; ++r) {
        const int row = m0 + i * 16 + g * 4 + r;
        if (MODE == 2) {
          ((float*)Cout)[(size_t)row * N + col] = acc[i][j][r] + bj;
        } else if (MODE == 1) {
          const size_t orow = (size_t)(row >> 10) * 1025 + 1 + (row & 1023);
          ((__bf16*)Cout)[orow * 1024 + col] = (__bf16)acc[i][j][r];
        } else if (MODE == 4) {
          ((__bf16*)Cout)[(size_t)row * N + col] = (__bf16)(acc[i][j][r] * ATTN_SC);
        } else {
          ((__bf16*)Cout)[(size_t)row * N + col] = (__bf16)acc[i][j][r];
        }
      }
  }
}

// fused conv-GEMM (128 tiles, K=3072) + Q-GEMM (384 tiles, K=1024), XCD-grouped.
__global__ __launch_bounds__(256, 2) void gemm_convq_kernel(
    const __bf16* __restrict__ xb, const __bf16* __restrict__ wc2,
    const __bf16* __restrict__ wqb, __bf16* __restrict__ ktmp, __bf16* __restrict__ qb)
{
  __shared__ __attribute__((aligned(16))) __bf16 As[12288];   // 3 x 8 KB
  __shared__ __attribute__((aligned(16))) __bf16 Bs[24576];   // 3 x 16 KB
  const int xcd = blockIdx.x & 7, s = blockIdx.x >> 3;
  if (s < 16) {
    const int id = xcd * 16 + s;
    gemm4_body<1>(xb, wc2, ktmp, nullptr, 1024, 3072, (id >> 2) * 128, (id & 3) * 256, As, Bs);
  } else {
    const int id = xcd * 48 + (s - 16);
    gemm4_body<4>(xb, wqb, qb, nullptr, 1024, 1024, (id >> 2) * 128, (id & 3) * 256, As, Bs);
  }
}

// K + V projections: 33 row-tiles x 4 col-tiles x 2 proj = 264 blocks, XCD-grouped.
__global__ __launch_bounds__(256, 2) void gemm_kv_kernel(
    const __bf16* __restrict__ ktmp, const __bf16* __restrict__ wkb,
    const __bf16* __restrict__ wvb, __bf16* __restrict__ kb, __bf16* __restrict__ vb)
{
  __shared__ __attribute__((aligned(16))) __bf16 As[12288];
  __shared__ __attribute__((aligned(16))) __bf16 Bs[24576];
  const int id = (blockIdx.x & 7) * 33 + (blockIdx.x >> 3);
  const int p  = (id >= 132) ? 1 : 0;
  const int rest = id - p * 132;
  gemm4_body<0>(ktmp, p ? wvb : wkb, p ? vb : kb, nullptr, 1024, 1024,
                (rest >> 2) * 128, (rest & 3) * 256, As, Bs);
}

__global__ __launch_bounds__(256, 2) void gemm_o_kernel(
    const __bf16* __restrict__ ob, const __bf16* __restrict__ wob,
    float* __restrict__ out, const float* __restrict__ bo)
{
  __shared__ __attribute__((aligned(16))) __bf16 As[12288];
  __shared__ __attribute__((aligned(16))) __bf16 Bs[24576];
  const int id = (blockIdx.x & 7) * 48 + (blockIdx.x >> 3);
  gemm4_body<2>(ob, wob, out, bo, 1024, 1024, (id >> 2) * 128, (id & 3) * 256, As, Bs);
}

// ---------------- flash attention (unchanged from r6) ----------------

__global__ __launch_bounds__(256) void attn_kernel(
    const __bf16* __restrict__ Q, const __bf16* __restrict__ Kk,
    const __bf16* __restrict__ Vt, __bf16* __restrict__ O)
{
  __shared__ __attribute__((aligned(16))) __bf16 Kd[2][64 * 64];  // [key][d]
  __shared__ __attribute__((aligned(16))) __bf16 Vd[2][64 * 64];  // [d][key]
  __shared__ __attribute__((aligned(16))) __bf16 Ps[4][32 * 64];

  const int tid  = threadIdx.x;
  const int wave = tid >> 6;
  const int lane = tid & 63;
  const int g    = lane >> 4;
  const int ln   = lane & 15;

  const int l    = blockIdx.x;
  const int xcd  = l & 7;
  const int b    = xcd >> 1;
  const int rest = l >> 3;
  const int h    = rest & 15;
  const int qt   = ((11 - (rest >> 4)) << 1) | (xcd & 1);
  const int q0   = qt * 128 + wave * 32;

  const size_t qrow0 = (size_t)b * 3072 + q0;
  const size_t krow0 = (size_t)b * 1025;
  const size_t vtrow = ((size_t)(b * 16 + h)) * 64;
  const int hc = h * 64;
  const int sw = (ln & 7) << 3;
  __bf16* Pw = Ps[wave];

  const int srow = lane >> 3;
  const int scol = (lane & 7) * 8;

  auto stage = [&](int kt, int bb) {
    const int kb0 = kt * 64;
#pragma unroll
    for (int i = 0; i < 2; ++i) {
      const int rr = (wave * 2 + i) * 8 + srow;
      gload_lds16(Kk + (krow0 + kb0 + rr) * 1024 + hc + scol,
                  Kd[bb] + (size_t)rr * 64 + scol);
      gload_lds16(Vt + (vtrow + rr) * 1024 + kb0 + scol,
                  Vd[bb] + (size_t)rr * 64 + scol);
    }
  };

  bf16x8 qf[2][2];
#pragma unroll
  for (int i = 0; i < 2; ++i)
#pragma unroll
    for (int kc = 0; kc < 2; ++kc)
      qf[i][kc] = *(const bf16x8*)(Q + (qrow0 + i * 16 + ln) * 1024 + hc + kc * 32 + g * 8);

  floatx4 oacc[2][4];
  floatx4 oal[2];
#pragma unroll
  for (int i = 0; i < 2; ++i) {
    floatx4 z = {0.f, 0.f, 0.f, 0.f};
    oal[i] = z;
#pragma unroll
    for (int dt = 0; dt < 4; ++dt) oacc[i][dt] = z;
  }

  bf16x8 ones;
#pragma unroll
  for (int e = 0; e < 8; ++e) ones[e] = (__bf16)1.0f;

  const int nkt_blk = (((qt * 128 + 127) / 3) >> 6) + 1;
  const int nfull   = (q0 >= 189) ? ((q0 - 189) / 192 + 1) : 0;

  stage(0, 0);

  for (int kt = 0; kt < nkt_blk; ++kt) {
    const int bb = kt & 1;
    __syncthreads();
    if (kt + 1 < nkt_blk) stage(kt + 1, bb ^ 1);
    const int kb0 = kt * 64;
    const bool masked = (kt >= nfull);

    bf16x8 kf[4][2];
#pragma unroll
    for (int jk = 0; jk < 4; ++jk)
#pragma unroll
      for (int kc = 0; kc < 2; ++kc)
        kf[jk][kc] = *(const bf16x8*)(Kd[bb] + (jk * 16 + ln) * 64 + kc * 32 + g * 8);

#pragma unroll
    for (int jk = 0; jk < 4; ++jk)
#pragma unroll
      for (int i = 0; i < 2; ++i) {
        floatx4 s = {0.f, 0.f, 0.f, 0.f};
        s = MFMA16x16x32(kf[jk][0], qf[i][0], s);
        s = MFMA16x16x32(kf[jk][1], qf[i][1], s);
        float p[4];
#pragma unroll
        for (int r = 0; r < 4; ++r) {
          float e = __builtin_amdgcn_exp2f(s[r]);
          if (masked) {
            const int key = kb0 + jk * 16 + 4 * g + r;
            const int q   = q0 + i * 16 + ln;
            e = (3 * key <= q) ? e : 0.f;
          }
          p[r] = e;
        }
        bf16x4 pk;
        pk[0] = (__bf16)p[0]; pk[1] = (__bf16)p[1]; pk[2] = (__bf16)p[2]; pk[3] = (__bf16)p[3];
        *(bf16x4*)(Pw + (i * 16 + ln) * 64 + ((jk * 16 + 4 * g) ^ sw)) = pk;
      }

#pragma unroll
    for (int kc = 0; kc < 2; ++kc) {
      bf16x8 pf0 = *(const bf16x8*)(Pw + (ln) * 64      + ((kc * 32 + g * 8) ^ sw));
      bf16x8 pf1 = *(const bf16x8*)(Pw + (16 + ln) * 64 + ((kc * 32 + g * 8) ^ sw));
      oal[0] = MFMA16x16x32(ones, pf0, oal[0]);
      oal[1] = MFMA16x16x32(ones, pf1, oal[1]);
#pragma unroll
      for (int dt = 0; dt < 4; ++dt) {
        bf16x8 vf = *(const bf16x8*)(Vd[bb] + (dt * 16 + ln) * 64 + kc * 32 + g * 8);
        oacc[0][dt] = MFMA16x16x32(vf, pf0, oacc[0][dt]);
        oacc[1][dt] = MFMA16x16x32(vf, pf1, oacc[1][dt]);
      }
    }
  }

#pragma unroll
  for (int i = 0; i < 2; ++i) {
    const float inv = 1.0f / oal[i][0];
    const size_t row = qrow0 + i * 16 + ln;
#pragma unroll
    for (int dt = 0; dt < 4; ++dt) {
      bf16x4 o4;
#pragma unroll
      for (int r = 0; r < 4; ++r) o4[r] = (__bf16)(oacc[i][dt][r] * inv);
      *(bf16x4*)(O + row * 1024 + hc + dt * 16 + 4 * g) = o4;
    }
  }
}

// ---------------- host ----------------

extern "C" void kernel_launch(void* const* d_in, const int* in_sizes, int n_in,
                              void* d_out, int out_size, void* d_ws, size_t ws_size,
                              hipStream_t stream) {
  (void)in_sizes; (void)n_in; (void)out_size; (void)ws_size;
  const float* x     = (const float*)d_in[0];
  const float* Wq    = (const float*)d_in[1];
  const float* Wk    = (const float*)d_in[2];
  const float* Wv    = (const float*)d_in[3];
  const float* Wo    = (const float*)d_in[4];
  const float* bo    = (const float*)d_in[5];
  const float* Wconv = (const float*)d_in[6];

  char* ws = (char*)d_ws;
  const size_t SZ_XQ = (size_t)12288 * 1024 * 2;
  const size_t SZ_KT = (size_t)4224 * 1024 * 2;
  const size_t SZ_W  = (size_t)1024 * 1024 * 2;

  __bf16* xb   = (__bf16*)(ws);
  __bf16* qb   = (__bf16*)(ws + SZ_XQ);           // q proj (pre-scaled); attn output in-place
  __bf16* ktmp = (__bf16*)(ws + 2 * SZ_XQ);
  __bf16* kb   = (__bf16*)(ws + 2 * SZ_XQ + SZ_KT);
  __bf16* vb   = (__bf16*)(ws + 2 * SZ_XQ + 2 * SZ_KT);
  __bf16* wqb  = (__bf16*)(ws + 2 * SZ_XQ + 3 * SZ_KT);
  __bf16* wkb  = (__bf16*)(ws + 2 * SZ_XQ + 3 * SZ_KT + SZ_W);
  __bf16* wvb  = (__bf16*)(ws + 2 * SZ_XQ + 3 * SZ_KT + 2 * SZ_W);
  __bf16* wob  = (__bf16*)(ws + 2 * SZ_XQ + 3 * SZ_KT + 3 * SZ_W);
  __bf16* wc2  = (__bf16*)(ws + 2 * SZ_XQ + 3 * SZ_KT + 4 * SZ_W);
  __bf16* vt   = xb;  // xb dead after conv+q GEMMs; reuse for Vt (8.4 MB)

  prep_kernel<<<dim3(17424), dim3(256), 0, stream>>>(x, Wq, Wk, Wv, Wo, Wconv,
                                                     xb, wqb, wkb, wvb, wob, wc2, ktmp);
  gemm_convq_kernel<<<dim3(512), dim3(256), 0, stream>>>(xb, wc2, wqb, ktmp, qb);
  gemm_kv_kernel<<<dim3(264), dim3(256), 0, stream>>>(ktmp, wkb, wvb, kb, vb);
  vtrans_kernel<<<dim3(16, 64), dim3(256), 0, stream>>>(vb, vt);
  attn_kernel<<<dim3(1536), dim3(256), 0, stream>>>(qb, kb, vt, qb);
  gemm_o_kernel<<<dim3(384), dim3(256), 0, stream>>>(qb, wob, (float*)d_out, bo);
}